// Round 5
// baseline (368.813 us; speedup 1.0000x reference)
//
#include <hip/hip_runtime.h>
#include <math.h>

// ---- problem constants ----
// D = 640; NET1=[640,512,64]; NET3=[640,640,512,64,512]
// W_TOTAL = 802816 ; B_TOTAL = 1728 ; x2 rows = 804544, each 64 wide
// weight row offsets: L1 wi=0, L2 wi=409600, L3 wi=737280, L4 wi=770048
// bias rows: L1 802816, L2 803456, L3 803968, L4 804032

// workspace layout (float offsets)
#define WS_H0    0      // 640
#define WS_H1N1  640    // 512
#define WS_H1N2  1152   // 512
#define WS_H2    1664   // 64   : "h" for W3
#define WS_X3A   2368   // 640  : layer-1 raw accumulators (zeroed by memset)
#define WS_CNT   3008   // 16 uints : grid-barrier counters (zeroed by memset)
#define WS_X3B   3072   // 512
#define WS_X3C   3584   // 64
#define WS_T     4096   // 804544 : t[r] = 0.5*tanh(w3[r]·h + b3[r])

#define N_ROWS   804544
#define N_WAVES  12571   // N_ROWS / 64
#define L1_ROWS  409600
#define L1_WAVES 6400

__device__ __forceinline__ float leaky_f(float v) { return v >= 0.0f ? v : 0.01f * v; }

__device__ __forceinline__ float inpt_at(int i, const float* x, const float* po, const float* st) {
  return i < 64 ? x[i] : (i < 128 ? po[i - 64] : st[i - 128]);
}

// 0.5*tanh(d) = 0.5 - 1/(exp(2d)+1)
__device__ __forceinline__ float half_tanh(float d) {
  float t = exp2f(d * 2.8853900817779268f);  // exp(2d)
  return 0.5f - __builtin_amdgcn_rcpf(t + 1.0f);
}

// device-scope grid barrier: every block calls it; blocks must be co-resident.
// Standard CG-style pattern: block-sync, thread0 fence+arrive+spin, block-sync.
__device__ __forceinline__ void gbar(unsigned* cnt, unsigned target) {
  __syncthreads();
  if (threadIdx.x == 0) {
    __threadfence();                 // release all this block's prior writes (agent scope)
    atomicAdd(cnt, 1u);              // device-scope by default on gfx950
    while (__hip_atomic_load(cnt, __ATOMIC_RELAXED, __HIP_MEMORY_SCOPE_AGENT) < target) {
      __builtin_amdgcn_s_sleep(2);
    }
    __threadfence();                 // acquire: invalidate stale L1/L2 lines
  }
  __syncthreads();
}

// float4 dot of a row (IN floats) against LDS vector, wave-parallel
template <int IN>
__device__ __forceinline__ float row_dot(const float* __restrict__ wrow, const float* s_in, int lane) {
  const float4* w4 = (const float4*)wrow;
  const float4* s4 = (const float4*)s_in;
  float acc = 0.f;
  for (int j = lane; j < IN / 4; j += 64) {
    float4 a = w4[j];
    float4 b = s4[j];
    acc += a.x * b.x + a.y * b.y + a.z * b.z + a.w * b.w;
  }
  for (int off = 32; off; off >>= 1) acc += __shfl_xor(acc, off, 64);
  return acc;
}

// ---------- trunkCoop: all of net2 L0/L1/L2 and net1 in one kernel.
// 128 blocks x 256 threads (512 waves), 2 grid barriers.
__global__ __launch_bounds__(256) void trunkCoop(
    const float* __restrict__ x, const float* __restrict__ po, const float* __restrict__ st,
    const float* __restrict__ w2_0, const float* __restrict__ b2_0,
    const float* __restrict__ w2_1, const float* __restrict__ b2_1,
    const float* __restrict__ w2_2, const float* __restrict__ b2_2,
    const float* __restrict__ w1_0, const float* __restrict__ b1_0,
    const float* __restrict__ w1_1, const float* __restrict__ b1_1,
    float* __restrict__ ws, float* __restrict__ out, unsigned* __restrict__ cnt) {
  __shared__ __align__(16) float s_in[640];
  __shared__ __align__(16) float s_h0[640];
  __shared__ __align__(16) float s_h1[512];
  __shared__ __align__(16) float s_h2[512];
  const int tid = threadIdx.x;
  const int wave = tid >> 6, lane = tid & 63;
  const int gw = blockIdx.x * 4 + wave;  // 0..511

  // ---- phase A: h0[640] = leaky(w2_0@inpt+b), h1n1[512] = leaky(w1_0@inpt+b)
  for (int i = tid; i < 640; i += 256) s_in[i] = inpt_at(i, x, po, st);
  __syncthreads();
#pragma unroll
  for (int r = 0; r < 3; r++) {
    int o = gw + r * 512;
    if (o < 640) {
      float acc = row_dot<640>(w2_0 + (long long)o * 640, s_in, lane);
      if (lane == 0) ws[WS_H0 + o] = leaky_f(acc + b2_0[o]);
    } else if (o < 1152) {
      int oo = o - 640;
      float acc = row_dot<640>(w1_0 + (long long)oo * 640, s_in, lane);
      if (lane == 0) ws[WS_H1N1 + oo] = leaky_f(acc + b1_0[oo]);
    }
  }
  gbar(cnt + 0, 128);

  // ---- phase B: h1n2[512] = leaky(w2_1@h0+b) ; d_out[0:64] = w1_1@h1n1+b
  for (int i = tid; i < 640; i += 256) s_h0[i] = ws[WS_H0 + i];
  for (int i = tid; i < 512; i += 256) s_h1[i] = ws[WS_H1N1 + i];
  __syncthreads();
  {
    int o = gw;
    if (o < 512) {
      float acc = row_dot<640>(w2_1 + (long long)o * 640, s_h0, lane);
      if (lane == 0) ws[WS_H1N2 + o] = leaky_f(acc + b2_1[o]);
    }
    if (gw < 64) {
      float acc = row_dot<512>(w1_1 + (long long)gw * 512, s_h1, lane);
      if (lane == 0) out[gw] = acc + b1_1[gw];
    }
  }
  gbar(cnt + 1, 128);

  // ---- phase C: h2[64] = leaky(w2_2@h1n2+b)
  for (int i = tid; i < 512; i += 256) s_h2[i] = ws[WS_H1N2 + i];
  __syncthreads();
  if (gw < 64) {
    float acc = row_dot<512>(w2_2 + (long long)gw * 512, s_h2, lane);
    if (lane == 0) ws[WS_H2 + gw] = leaky_f(acc + b2_2[gw]);
  }
}

// ---------- bigT: t[r] = 0.5*tanh(w3[r,:]·h + b3[r]) for all rows, with
// generated layer 1 fused: rows < 409600 are consumed immediately as
// atomicAdd partials into x3a_raw (one atomic per wave), not written to t.
// One wave per 64 consecutive rows; 16 lanes cooperate per row.
__global__ __launch_bounds__(256) void bigT(const float* __restrict__ w3, const float* __restrict__ b3,
                                            const float* __restrict__ x, const float* __restrict__ po,
                                            const float* __restrict__ st,
                                            float* __restrict__ ws, float* __restrict__ t) {
  __shared__ __align__(16) float s_inpt[640];
  for (int i = threadIdx.x; i < 640; i += 256) s_inpt[i] = inpt_at(i, x, po, st);
  __syncthreads();

  const int wid = blockIdx.x * 4 + (threadIdx.x >> 6);
  if (wid >= N_WAVES) return;  // no barriers below
  const int lane = threadIdx.x & 63;
  const int g = lane >> 4;    // row-in-quad (0..3)
  const int gl = lane & 15;   // float4-slot within row
  const float4 hv = ((const float4*)(ws + WS_H2))[gl];
  const long long base = (long long)wid * 64;
  const float4* wp = (const float4*)(w3 + (base << 6));  // 64 rows x 16 float4

  const bool isL1 = (wid < L1_WAVES);
  const int o_l1 = wid / 10;               // output neuron (layer 1)
  const int ibase = (wid % 10) * 64;       // input index base

  float4 v[16];
#pragma unroll
  for (int q = 0; q < 16; q++) v[q] = wp[((q * 4 + g) << 4) + gl];

  float acc = 0.0f;
#pragma unroll
  for (int q = 0; q < 16; q++) {
    float d = v[q].x * hv.x + v[q].y * hv.y + v[q].z * hv.z + v[q].w * hv.w;
    d += __shfl_xor(d, 1, 64);
    d += __shfl_xor(d, 2, 64);
    d += __shfl_xor(d, 4, 64);
    d += __shfl_xor(d, 8, 64);
    if (gl == 0) {
      long long r = base + q * 4 + g;
      float tv = half_tanh(d + b3[r]);
      if (isL1) acc += tv * s_inpt[ibase + q * 4 + g];
      else t[r] = tv;
    }
  }
  if (isL1) {
    // sum the 4 per-quad partials (lanes 0,16,32,48; others hold 0)
    acc += __shfl_xor(acc, 16, 64);
    acc += __shfl_xor(acc, 32, 64);
    if (lane == 0) atomicAdd(&ws[WS_X3A + o_l1], acc);
  }
}

// ---------- gmlCoop: generated layers 2,3,4 from t (L2-resident).
// 64 blocks x 256 threads (256 waves), 2 grid barriers.
__global__ __launch_bounds__(256) void gmlCoop(const float* __restrict__ t, float* __restrict__ ws,
                                               float* __restrict__ out, unsigned* __restrict__ cnt) {
  __shared__ __align__(16) float s_a[640];
  __shared__ __align__(16) float s_b[512];
  __shared__ float s_red[4];
  const int tid = threadIdx.x;
  const int wave = tid >> 6, lane = tid & 63;
  const int gw = blockIdx.x * 4 + wave;  // 0..255

  // ---- layer 2: x3b[512] = leaky( t_L2 @ x3a + bias ), x3a = leaky(raw + t_bias1)
  for (int i = tid; i < 640; i += 256) s_a[i] = leaky_f(ws[WS_X3A + i] + t[802816 + i]);
  __syncthreads();
#pragma unroll
  for (int r = 0; r < 2; r++) {
    int o = gw + r * 256;  // 0..511
    float acc = row_dot<640>(t + 409600 + (long long)o * 640, s_a, lane);
    if (lane == 0) ws[WS_X3B + o] = leaky_f(acc + t[803456 + o]);
  }
  gbar(cnt + 2, 64);

  // ---- layer 3: x3c[64] = leaky( t_L3 @ x3b + bias ); one output per block
  for (int i = tid; i < 512; i += 256) s_b[i] = ws[WS_X3B + i];
  __syncthreads();
  {
    const int o = blockIdx.x;  // 0..63
    const float4* row = (const float4*)(t + 737280 + (long long)o * 512);
    const float4* bb = (const float4*)s_b;
    float a = 0.f;
    for (int j = tid; j < 128; j += 256) {  // threads 0..127 active
      float4 wv = row[j], bv = bb[j];
      a += wv.x * bv.x + wv.y * bv.y + wv.z * bv.z + wv.w * bv.w;
    }
    for (int off = 32; off; off >>= 1) a += __shfl_xor(a, off, 64);
    if (lane == 0) s_red[wave] = a;
    __syncthreads();
    if (tid == 0) {
      float tot = s_red[0] + s_red[1] + s_red[2] + s_red[3];
      ws[WS_X3C + o] = leaky_f(tot + t[803968 + o]);
    }
  }
  gbar(cnt + 3, 64);

  // ---- layer 4: d_out[64+o] = t_L4 @ x3c + bias (no activation)
  float xc = ws[WS_X3C + lane];
#pragma unroll
  for (int r = 0; r < 2; r++) {
    int o = gw + r * 256;  // 0..511
    float a = t[770048 + (long long)o * 64 + lane] * xc;
    for (int off = 32; off; off >>= 1) a += __shfl_xor(a, off, 64);
    if (lane == 0) out[64 + o] = a + t[804032 + o];
  }
}

extern "C" void kernel_launch(void* const* d_in, const int* in_sizes, int n_in,
                              void* d_out, int out_size, void* d_ws, size_t ws_size,
                              hipStream_t stream) {
  const float* x    = (const float*)d_in[0];
  const float* po   = (const float*)d_in[1];
  const float* st   = (const float*)d_in[2];
  const float* w1_0 = (const float*)d_in[3];
  const float* b1_0 = (const float*)d_in[4];
  const float* w1_1 = (const float*)d_in[5];
  const float* b1_1 = (const float*)d_in[6];
  const float* w2_0 = (const float*)d_in[7];
  const float* b2_0 = (const float*)d_in[8];
  const float* w2_1 = (const float*)d_in[9];
  const float* b2_1 = (const float*)d_in[10];
  const float* w2_2 = (const float*)d_in[11];
  const float* b2_2 = (const float*)d_in[12];
  const float* w3   = (const float*)d_in[13];
  const float* b3   = (const float*)d_in[14];
  float* ws  = (float*)d_ws;
  float* out = (float*)d_out;
  float* t   = ws + WS_T;
  unsigned* cnt = (unsigned*)(ws + WS_CNT);

  // zero layer-1 accumulators + barrier counters (capture-legal memset node)
  hipMemsetAsync(ws + WS_X3A, 0, (640 + 16) * sizeof(float), stream);

  trunkCoop<<<128, 256, 0, stream>>>(x, po, st, w2_0, b2_0, w2_1, b2_1, w2_2, b2_2,
                                     w1_0, b1_0, w1_1, b1_1, ws, out, cnt);
  bigT<<<(N_WAVES + 3) / 4, 256, 0, stream>>>(w3, b3, x, po, st, ws, t);
  gmlCoop<<<64, 256, 0, stream>>>(t, ws, out, cnt);
}

// Round 7
// 335.799 us; speedup vs baseline: 1.0983x; 1.0983x over previous
//
#include <hip/hip_runtime.h>
#include <math.h>

// ---- problem constants ----
// D = 640; NET1=[640,512,64]; NET3=[640,640,512,64,512]
// W_TOTAL = 802816 ; B_TOTAL = 1728 ; x2 rows = 804544, each 64 wide
// weight row offsets: L1 wi=0, L2 wi=409600, L3 wi=737280, L4 wi=770048
// bias rows: L1 802816, L2 803456, L3 803968, L4 804032

// workspace layout (float offsets)
#define WS_H0    0      // 640
#define WS_H1N1  640    // 512
#define WS_H1N2  1152   // 512
#define WS_H2    1664   // 64   : "h" for W3
#define WS_INPT  1728   // 640
#define WS_X3A   2368   // 640
#define WS_X3B   3008   // 512
#define WS_T     4096   // 804544 : t[r] = 0.5*tanh(w3[r]·h + b3[r])

#define N_ROWS   804544
#define N_WAVES  12571   // N_ROWS / 64

typedef float vf4 __attribute__((ext_vector_type(4)));  // native vec for nontemporal builtins

__device__ __forceinline__ float leaky_f(float v) { return v >= 0.0f ? v : 0.01f * v; }

__device__ __forceinline__ float inpt_at(int i, const float* x, const float* po, const float* st) {
  return i < 64 ? x[i] : (i < 128 ? po[i - 64] : st[i - 128]);
}

// 0.5*tanh(d) = 0.5 - 1/(exp(2d)+1)
__device__ __forceinline__ float half_tanh(float d) {
  float t = exp2f(d * 2.8853900817779268f);  // exp(2d)
  return 0.5f - __builtin_amdgcn_rcpf(t + 1.0f);
}

// float4 dot of a row (IN floats) against LDS vector, wave-parallel
template <int IN>
__device__ __forceinline__ float row_dot(const float* __restrict__ wrow, const float* s_in, int lane) {
  const float4* w4 = (const float4*)wrow;
  const float4* s4 = (const float4*)s_in;
  float acc = 0.f;
  for (int j = lane; j < IN / 4; j += 64) {
    float4 a = w4[j];
    float4 b = s4[j];
    acc += a.x * b.x + a.y * b.y + a.z * b.z + a.w * b.w;
  }
  for (int off = 32; off; off >>= 1) acc += __shfl_xor(acc, off, 64);
  return acc;
}

// ---------- K1a: h0 = leaky(net2_w0@inpt+b0) [640], h1n1 = leaky(net1_w0@inpt+b0) [512]
__global__ __launch_bounds__(256) void k1a(const float* __restrict__ x, const float* __restrict__ po,
                                           const float* __restrict__ st,
                                           const float* __restrict__ w2_0, const float* __restrict__ b2_0,
                                           const float* __restrict__ w1_0, const float* __restrict__ b1_0,
                                           float* __restrict__ ws) {
  __shared__ __align__(16) float s_in[640];
  for (int i = threadIdx.x; i < 640; i += 256) {
    float v = inpt_at(i, x, po, st);
    s_in[i] = v;
    ws[WS_INPT + i] = v;
  }
  __syncthreads();
  int wave = threadIdx.x >> 6, lane = threadIdx.x & 63;
  int o = blockIdx.x * 4 + wave;  // 0..1151
  const float* wrow;
  float bias;
  float* dst;
  if (o < 640) {
    wrow = w2_0 + (long long)o * 640; bias = b2_0[o]; dst = ws + WS_H0 + o;
  } else {
    int oo = o - 640;
    wrow = w1_0 + (long long)oo * 640; bias = b1_0[oo]; dst = ws + WS_H1N1 + oo;
  }
  float acc = row_dot<640>(wrow, s_in, lane);
  if (lane == 0) *dst = leaky_f(acc + bias);
}

// ---------- K1b: h1n2 = leaky(net2_w1@h0+b1) [512] ; out = net1_w1@h1n1+b1 [64]
__global__ __launch_bounds__(256) void k1b(const float* __restrict__ w2_1, const float* __restrict__ b2_1,
                                           const float* __restrict__ w1_1, const float* __restrict__ b1_1,
                                           float* __restrict__ ws, float* __restrict__ out) {
  __shared__ __align__(16) float s_h0[640];
  __shared__ __align__(16) float s_h1[512];
  for (int i = threadIdx.x; i < 640; i += 256) s_h0[i] = ws[WS_H0 + i];
  for (int i = threadIdx.x; i < 512; i += 256) s_h1[i] = ws[WS_H1N1 + i];
  __syncthreads();
  int wave = threadIdx.x >> 6, lane = threadIdx.x & 63;
  int o = blockIdx.x * 4 + wave;  // 0..575
  if (o < 512) {
    float acc = row_dot<640>(w2_1 + (long long)o * 640, s_h0, lane);
    if (lane == 0) ws[WS_H1N2 + o] = leaky_f(acc + b2_1[o]);
  } else {
    int oo = o - 512;
    float acc = row_dot<512>(w1_1 + (long long)oo * 512, s_h1, lane);
    if (lane == 0) out[oo] = acc + b1_1[oo];
  }
}

// ---------- K1c: h2 = leaky(net2_w2@h1n2+b2) [64]
__global__ __launch_bounds__(256) void k1c(const float* __restrict__ w2_2, const float* __restrict__ b2_2,
                                           float* __restrict__ ws) {
  __shared__ __align__(16) float s_h[512];
  for (int i = threadIdx.x; i < 512; i += 256) s_h[i] = ws[WS_H1N2 + i];
  __syncthreads();
  int wave = threadIdx.x >> 6, lane = threadIdx.x & 63;
  int o = blockIdx.x * 4 + wave;  // 0..63
  float acc = row_dot<512>(w2_2 + (long long)o * 512, s_h, lane);
  if (lane == 0) ws[WS_H2 + o] = leaky_f(acc + b2_2[o]);
}

// ---------- bigT: t[r] = 0.5*tanh(w3[r,:]·h + b3[r]) for ALL 804544 rows.
// Zero inter-row dependency; one wave per 64 consecutive rows; 16 lanes/row.
// Nontemporal loads: w3 is streamed once, keep L2 free for t.
__global__ __launch_bounds__(256) void bigT(const float* __restrict__ w3, const float* __restrict__ b3,
                                            const float* __restrict__ h2p, float* __restrict__ t) {
  int wid = blockIdx.x * 4 + (threadIdx.x >> 6);
  if (wid >= N_WAVES) return;  // no barriers below: early return safe
  const int lane = threadIdx.x & 63;
  const int g = lane >> 4;    // row-in-quad (0..3)
  const int gl = lane & 15;   // float4-slot within row
  float4 hv = ((const float4*)h2p)[gl];
  const long long base = (long long)wid * 64;
  const vf4* wp = (const vf4*)(w3 + (base << 6));  // 64 rows x 16 vec4
  vf4 v[16];
#pragma unroll
  for (int q = 0; q < 16; q++) v[q] = __builtin_nontemporal_load(&wp[((q * 4 + g) << 4) + gl]);
#pragma unroll
  for (int q = 0; q < 16; q++) {
    float d = v[q].x * hv.x + v[q].y * hv.y + v[q].z * hv.z + v[q].w * hv.w;
    d += __shfl_xor(d, 1, 64);
    d += __shfl_xor(d, 2, 64);
    d += __shfl_xor(d, 4, 64);
    d += __shfl_xor(d, 8, 64);
    if (gl == 0) {
      long long r = base + q * 4 + g;
      t[r] = half_tanh(d + b3[r]);
    }
  }
}

// ---------- gml: generated layer from precomputed t (L2-resident, 3.2 MB).
// x3out[o] = act( dot(t[wi+o*IN .. ], x3in) + t[brow+o] ), wave per output.
template <int IN, bool LEAKY>
__global__ __launch_bounds__(256) void gml(const float* __restrict__ t, const float* __restrict__ x3in,
                                           float* __restrict__ x3out, long long wi, long long brow,
                                           int OUT) {
  __shared__ __align__(16) float s_in[IN];
  for (int i = threadIdx.x; i < IN; i += 256) s_in[i] = x3in[i];
  __syncthreads();
  int wave = threadIdx.x >> 6, lane = threadIdx.x & 63;
  int o = blockIdx.x * 4 + wave;
  if (o >= OUT) return;
  float acc = row_dot<IN>(t + wi + (long long)o * IN, s_in, lane);
  if (lane == 0) {
    acc += t[brow + o];  // generated bias
    x3out[o] = LEAKY ? leaky_f(acc) : acc;
  }
}

// ---------- gmlTail: generated layers 3 (64<-512) and 4 (512<-64) in ONE block.
// 1024 threads = 16 waves; __syncthreads between phases (no device barrier).
__global__ __launch_bounds__(1024) void gmlTail(const float* __restrict__ t, const float* __restrict__ ws,
                                                float* __restrict__ out) {
  __shared__ __align__(16) float s_b[512];  // x3b
  __shared__ __align__(16) float s_c[64];   // x3c
  const int tid = threadIdx.x;
  const int wave = tid >> 6, lane = tid & 63;  // wave 0..15
  for (int i = tid; i < 512; i += 1024) s_b[i] = ws[WS_X3B + i];
  __syncthreads();
  // layer 3: one wave per output, 4 rounds
#pragma unroll
  for (int r = 0; r < 4; r++) {
    int o = wave + r * 16;  // 0..63
    float acc = row_dot<512>(t + 737280 + (long long)o * 512, s_b, lane);
    if (lane == 0) s_c[o] = leaky_f(acc + t[803968 + o]);
  }
  __syncthreads();
  // layer 4: 16-lane coop, 4 outputs/wave/round, 8 rounds; no activation
  const int g = lane >> 4, gl = lane & 15;
  float4 xc4 = ((const float4*)s_c)[gl];
#pragma unroll
  for (int r = 0; r < 8; r++) {
    int o = r * 64 + wave * 4 + g;  // 0..511
    const float4* row = (const float4*)(t + 770048 + (long long)o * 64);
    float4 wv = row[gl];
    float a = wv.x * xc4.x + wv.y * xc4.y + wv.z * xc4.z + wv.w * xc4.w;
    a += __shfl_xor(a, 1, 64);
    a += __shfl_xor(a, 2, 64);
    a += __shfl_xor(a, 4, 64);
    a += __shfl_xor(a, 8, 64);
    if (gl == 0) out[64 + o] = a + t[804032 + o];
  }
}

extern "C" void kernel_launch(void* const* d_in, const int* in_sizes, int n_in,
                              void* d_out, int out_size, void* d_ws, size_t ws_size,
                              hipStream_t stream) {
  const float* x    = (const float*)d_in[0];
  const float* po   = (const float*)d_in[1];
  const float* st   = (const float*)d_in[2];
  const float* w1_0 = (const float*)d_in[3];
  const float* b1_0 = (const float*)d_in[4];
  const float* w1_1 = (const float*)d_in[5];
  const float* b1_1 = (const float*)d_in[6];
  const float* w2_0 = (const float*)d_in[7];
  const float* b2_0 = (const float*)d_in[8];
  const float* w2_1 = (const float*)d_in[9];
  const float* b2_1 = (const float*)d_in[10];
  const float* w2_2 = (const float*)d_in[11];
  const float* b2_2 = (const float*)d_in[12];
  const float* w3   = (const float*)d_in[13];
  const float* b3   = (const float*)d_in[14];
  float* ws  = (float*)d_ws;
  float* out = (float*)d_out;
  float* t   = ws + WS_T;

  k1a<<<288, 256, 0, stream>>>(x, po, st, w2_0, b2_0, w1_0, b1_0, ws);
  k1b<<<144, 256, 0, stream>>>(w2_1, b2_1, w1_1, b1_1, ws, out);
  k1c<<<16, 256, 0, stream>>>(w2_2, b2_2, ws);
  // the one heavy kernel: 206 MB streamed, fully parallel
  bigT<<<(N_WAVES + 3) / 4, 256, 0, stream>>>(w3, b3, ws + WS_H2, t);
  // generated net on L2-resident t
  gml<640, true><<<160, 256, 0, stream>>>(t, ws + WS_INPT, ws + WS_X3A, 0LL, 802816LL, 640);
  gml<640, true><<<128, 256, 0, stream>>>(t, ws + WS_X3A, ws + WS_X3B, 409600LL, 803456LL, 512);
  gmlTail<<<1, 1024, 0, stream>>>(t, ws, out);
}